// Round 4
// baseline (236.135 us; speedup 1.0000x reference)
//
#include <hip/hip_runtime.h>
#include <hip/hip_bf16.h>
#include <type_traits>

typedef __attribute__((ext_vector_type(8))) _Float16 half8;
typedef __attribute__((ext_vector_type(4))) _Float16 half4;
typedef __attribute__((ext_vector_type(2))) _Float16 half2;
typedef __attribute__((ext_vector_type(4))) float f32x4;

constexpr int CB = 48, CS = 128, CW = 4, CK = 256;

// eT[b][k][kp] = exp(T[b][k][kp] * tag_mask[b][k][kp]) as f16, float4-vectorized
__global__ void prep_eT_kernel(const f32x4* __restrict__ T,
                               const f32x4* __restrict__ tm,
                               half4* __restrict__ eT, int n4) {
    int i = blockIdx.x * 256 + threadIdx.x;
    if (i < n4) {
        f32x4 t = T[i], m = tm[i];
        half4 o;
        o[0] = (_Float16)__expf(t[0] * m[0]);
        o[1] = (_Float16)__expf(t[1] * m[1]);
        o[2] = (_Float16)__expf(t[2] * m[2]);
        o[3] = (_Float16)__expf(t[3] * m[3]);
        eT[i] = o;
    }
}

__global__ __launch_bounds__(256, 1)
void crf_scan_kernel(const float* __restrict__ logits,
                     const float* __restrict__ ham,
                     const _Float16* __restrict__ eT,
                     const float* __restrict__ tag_mask,
                     const int* __restrict__ text_mask,
                     float* __restrict__ out) {
    const int b = blockIdx.x;
    const int tid = (int)threadIdx.x;
    const int wv = tid >> 6;
    const int lane = tid & 63;

    // double-buffered e row (f16) + per-wave partial sums of e (f32)
    __shared__ alignas(16) _Float16 ebuf[2][CK];
    __shared__ alignas(16) float red[2][4];
    __shared__ int len_s;

    ebuf[1][tid] = (_Float16)1.0f;   // e(alpha_{-1}) = exp(0 - 0) = 1, M_{-1} = 0
    ebuf[0][tid] = (_Float16)0.0f;
    if (tid < 4) { red[0][tid] = 0.0f; red[1][tid] = 64.0f; }  // sum e_{-1} = 256
    if (tid == 0) len_s = 0;
    __syncthreads();
    if (tid < CS) atomicAdd(&len_s, text_mask[b * CS + tid]);

    const float tm0 = tag_mask[(size_t)b * CK * CK + tid];  // tag_mask[b,0,k]

    // thread k = tid permanently holds eT row k: eT[b][k][0..255] as 32 half8 (128 VGPRs)
    half8 etv[32];
    {
        const _Float16* rowp = eT + (size_t)b * CK * CK + (size_t)tid * CK;
#pragma unroll
        for (int c = 0; c < 32; ++c) etv[c] = *(const half8*)(rowp + 8 * c);
    }

    const float* lgb = logits + (size_t)b * CS * CW * CK;
    const float* hcb = ham    + (size_t)b * CS * CW * CK;

    // wave-uniform scan state
    float Mn = 0.0f, M1 = 0.0f, M2 = 0.0f, M3 = 0.0f; // normalizers of alpha_{j-1..j-4}
    float y1 = 0.0f, y2 = 0.0f, y3 = 0.0f;            // y rows of alpha_{j-2..j-4} (thread's k)
    float ls_prev = __logf(256.0f) - 2.0f;            // seeds delta = 2 at j = 0
    float out_r = __logf(256.0f);                     // ls[0] (len == 0 case)

    // emissions for j = 0
    float em_cur[4];
#pragma unroll
    for (int w = 0; w < 4; ++w)
        em_cur[w] = (lgb[w * CK + tid] + hcb[w * CK + tid]) * tm0;

    __syncthreads();
    const int len = len_s;

    auto step = [&](int j, auto prc) {
        constexpr int PR = prc.value;       // parity read this step ((j+1)&1)
        constexpr int PW = PR ^ 1;          // parity written (j&1)

        // partial sums of e_{j-1} (written last step)
        f32x4 redv = *(const f32x4*)(&red[PR][0]);

        // prefetch emissions for j+1 (vmcnt stays in flight across the raw barrier)
        int jn = (j + 1 < CS) ? j + 1 : 0;  // wave-uniform clamp
        float lgn[4], hcn[4];
#pragma unroll
        for (int w = 0; w < 4; ++w) {
            int idx = jn * (CW * CK) + w * CK + tid;
            lgn[w] = lgb[idx];
            hcn[w] = hcb[idx];
        }

        // y_new[k] = sum_kp e_{j-1}[kp] * eT[k][kp]  — broadcast LDS reads vs register row
        float a0 = 0.0f, a1 = 0.0f, a2 = 0.0f, a3 = 0.0f;
#pragma unroll
        for (int g = 0; g < 8; ++g) {
            half8 ev[4];
#pragma unroll
            for (int c = 0; c < 4; ++c)
                ev[c] = *(const half8*)(&ebuf[PR][(g * 4 + c) * 8]);
#pragma unroll
            for (int c = 0; c < 4; ++c) {
                const int ch = g * 4 + c;
                half2 e0 = {ev[c][0], ev[c][1]}, t0 = {etv[ch][0], etv[ch][1]};
                half2 e1 = {ev[c][2], ev[c][3]}, t1 = {etv[ch][2], etv[ch][3]};
                half2 e2 = {ev[c][4], ev[c][5]}, t2 = {etv[ch][4], etv[ch][5]};
                half2 e3 = {ev[c][6], ev[c][7]}, t3 = {etv[ch][6], etv[ch][7]};
                a0 = __builtin_amdgcn_fdot2(e0, t0, a0, false);
                a1 = __builtin_amdgcn_fdot2(e1, t1, a1, false);
                a2 = __builtin_amdgcn_fdot2(e2, t2, a2, false);
                a3 = __builtin_amdgcn_fdot2(e3, t3, a3, false);
            }
        }
        float y_new = (a0 + a1) + (a2 + a3);

        // wave-uniform ls chain (overlaps the dot)
        float sum_prev = (redv[0] + redv[1]) + (redv[2] + redv[3]);
        float lsj = Mn + __logf(sum_prev);          // reference ls[j]
        if (j == len) out_r = lsj;
        float delta = lsj - ls_prev;
        ls_prev = lsj;
        float Mj = lsj + delta;                      // predicted normalizer for alpha_j
        float C = Mn;

        // alpha = C + log(S); S = sum_w y_w * exp(M_w + em_w - C)
        float S;
        {   // w = 0 (newest row alpha_{j-1})
            float yv = y_new;
            if (j == 0) yv = 256.0f;                 // initial-state path (no transition)
            S = yv * __expf(Mn + em_cur[0] - C);
        }
        {   // w = 1
            float yv = y1;
            if (j < 4) yv = (j == 1) ? 256.0f : (j < 1 ? 0.0f : yv);
            S = fmaf(yv, __expf(M1 + em_cur[1] - C), S);
        }
        {   // w = 2
            float yv = y2;
            if (j < 4) yv = (j == 2) ? 256.0f : (j < 2 ? 0.0f : yv);
            S = fmaf(yv, __expf(M2 + em_cur[2] - C), S);
        }
        {   // w = 3
            float yv = y3;
            if (j < 4) yv = (j == 3) ? 256.0f : (j < 3 ? 0.0f : yv);
            S = fmaf(yv, __expf(M3 + em_cur[3] - C), S);
        }
        float e = S * __expf(C - Mj);                // exp(alpha_j - Mj), fits f16
        ebuf[PW][tid] = (_Float16)e;

        // per-wave partial sum of e (consumed NEXT step -> off critical path)
        float ps = e;
#pragma unroll
        for (int o = 1; o < 64; o <<= 1) ps += __shfl_xor(ps, o, 64);
        if (lane == 0) red[PW][wv] = ps;

        // ring shift
        y3 = y2; y2 = y1; y1 = y_new;
        M3 = M2; M2 = M1; M1 = Mn; Mn = Mj;

        // rotate prefetched emissions
#pragma unroll
        for (int w = 0; w < 4; ++w)
            em_cur[w] = (lgn[w] + hcn[w]) * tm0;

        // raw barrier: drain LDS only; emission loads stay in flight (no vmcnt(0))
        asm volatile("s_waitcnt expcnt(0) lgkmcnt(0)\n\ts_barrier" ::: "memory");
    };

    for (int j = 0; j < CS; j += 2) {
        step(j,     std::integral_constant<int, 1>{});
        step(j + 1, std::integral_constant<int, 0>{});
    }

    // ls[128] = M_127 + log(sum_k e_127); partials are in red[1] (j=127 wrote PW=1)
    if (tid == 0) {
        float tot = (red[1][0] + red[1][1]) + (red[1][2] + red[1][3]);
        float ls_full = Mn + __logf(tot);
        if (len == CS) out_r = ls_full;
        out[b] = out_r;
    }
}

extern "C" void kernel_launch(void* const* d_in, const int* in_sizes, int n_in,
                              void* d_out, int out_size, void* d_ws, size_t ws_size,
                              hipStream_t stream) {
    const float* logits    = (const float*)d_in[0];
    const float* T         = (const float*)d_in[1];
    const float* ham       = (const float*)d_in[2];
    const float* tag_mask  = (const float*)d_in[3];
    const int*   text_mask = (const int*)d_in[4];
    float* out = (float*)d_out;

    _Float16* eT = (_Float16*)d_ws;  // CB*CK*CK f16 = 6.3 MB scratch
    int n4 = CB * CK * CK / 4;
    prep_eT_kernel<<<(n4 + 255) / 256, 256, 0, stream>>>(
        (const f32x4*)T, (const f32x4*)tag_mask, (half4*)eT, n4);
    crf_scan_kernel<<<CB, 256, 0, stream>>>(logits, ham, eT, tag_mask, text_mask, out);
}

// Round 6
// 216.886 us; speedup vs baseline: 1.0888x; 1.0888x over previous
//
#include <hip/hip_runtime.h>
#include <type_traits>
#include <cstdint>

typedef __attribute__((ext_vector_type(2))) _Float16 half2;
typedef __attribute__((ext_vector_type(4))) float f32x4;

constexpr int CB = 48, CS = 128, CW = 4, CK = 256;

__global__ __launch_bounds__(256, 1)
void crf_scan_kernel(const float* __restrict__ logits,
                     const float* __restrict__ T,
                     const float* __restrict__ ham,
                     const float* __restrict__ tag_mask,
                     const int* __restrict__ text_mask,
                     float* __restrict__ out) {
    const int b = blockIdx.x;
    const int tid = (int)threadIdx.x;
    const int wv = tid >> 6;      // wave: owns kp-chunk [64wv,64wv+64) and outputs k=64wv+lane
    const int lane = tid & 63;

    __shared__ float plds[2][4][4][64];  // [parity][src wave][g][lane] partial dots
    __shared__ f32x4 redl[2];            // per-wave partial sums of e, [parity]
    __shared__ int len_s;

    if (tid == 0) len_s = 0;
    __syncthreads();
    if (tid < CS) atomicAdd(&len_s, text_mask[b * CS + tid]);
    if (tid == 0) redl[1] = (f32x4){64.0f, 64.0f, 64.0f, 64.0f};  // sum e_{-1} = 256

    const float tm0 = tag_mask[(size_t)b * CK * CK + tid];  // tag_mask[b,0,k], k=tid

    // Register-resident transition slice (fused prep):
    // etp[g][i] = f16 pair ( eT[64g+lane][64wv+2i], eT[64g+lane][64wv+2i+1] ),
    // eT = exp(T * tag_mask). 128 VGPRs, held for all 128 steps.
    half2 etp[4][32];
    {
        const float* Tb = T + (size_t)b * CK * CK;
        const float* mb = tag_mask + (size_t)b * CK * CK;
#pragma unroll
        for (int g = 0; g < 4; ++g) {
            const float* tp = Tb + (64 * g + lane) * CK + 64 * wv;
            const float* mp = mb + (64 * g + lane) * CK + 64 * wv;
#pragma unroll
            for (int q = 0; q < 16; ++q) {
                f32x4 t = *(const f32x4*)(tp + 4 * q);
                f32x4 m = *(const f32x4*)(mp + 4 * q);
                float e0 = __expf(t[0] * m[0]), e1 = __expf(t[1] * m[1]);
                float e2 = __expf(t[2] * m[2]), e3 = __expf(t[3] * m[3]);
                etp[g][2 * q]     = __builtin_bit_cast(half2, __builtin_amdgcn_cvt_pkrtz(e0, e1));
                etp[g][2 * q + 1] = __builtin_bit_cast(half2, __builtin_amdgcn_cvt_pkrtz(e2, e3));
            }
        }
    }

    const float* lgb = logits + (size_t)b * CS * CW * CK;
    const float* hcb = ham    + (size_t)b * CS * CW * CK;

    // wave-uniform scan state
    float Mn = 0.0f, M1 = 0.0f, M2 = 0.0f, M3 = 0.0f;  // normalizers of alpha_{j-1..j-4}
    float y1 = 0.0f, y2 = 0.0f, y3 = 0.0f;             // y(alpha_{j-2..j-4}) at this thread's k
    float ls_prev = __logf(256.0f) - 2.0f;             // seeds delta = 2 at j = 0
    float out_r = __logf(256.0f);                      // ls[0] (len == 0 case)

    float em_cur[4];
#pragma unroll
    for (int w = 0; w < 4; ++w)
        em_cur[w] = (lgb[w * CK + tid] + hcb[w * CK + tid]) * tm0;

    // packed e_{j-1} pair for this lane's 2-group; e_{-1} = ones
    uint32_t pk = 0x3c003c00u;  // (1.0h, 1.0h)

    __syncthreads();
    const int len = len_s;

    auto step = [&](int j, auto pc) {
        constexpr int P = pc.value;  // j & 1

        // dot phase: y_j partials over this wave's kp chunk, e broadcast via readlane->SGPR
        float ac[8] = {0, 0, 0, 0, 0, 0, 0, 0};
#pragma unroll
        for (int i = 0; i < 16; ++i) {
            uint32_t s0 = (uint32_t)__builtin_amdgcn_readlane((int)pk, 2 * i);
            uint32_t s1 = (uint32_t)__builtin_amdgcn_readlane((int)pk, 2 * i + 32);
            half2 h0 = __builtin_bit_cast(half2, s0);
            half2 h1 = __builtin_bit_cast(half2, s1);
#pragma unroll
            for (int g = 0; g < 4; ++g) {
                ac[g]     = __builtin_amdgcn_fdot2(etp[g][i],      h0, ac[g],     false);
                ac[g + 4] = __builtin_amdgcn_fdot2(etp[g][i + 16], h1, ac[g + 4], false);
            }
        }

        // emission prefetch for j+1 (stays in flight across the barrier; no vmcnt drain)
        int jn = (j + 1 < CS) ? j + 1 : 0;
        float lgn[4], hcn[4];
#pragma unroll
        for (int w = 0; w < 4; ++w) {
            int idx = jn * (CW * CK) + w * CK + tid;
            lgn[w] = lgb[idx];
            hcn[w] = hcb[idx];
        }

        // publish partials (conflict-free: lane-stride 4B)
#pragma unroll
        for (int g = 0; g < 4; ++g)
            plds[P][wv][g][lane] = ac[g] + ac[g + 4];

        // drain LDS only; global loads stay in flight
        asm volatile("s_waitcnt expcnt(0) lgkmcnt(0)\n\ts_barrier" ::: "memory");

        // combine: y_j at this thread's k = 64*wv + lane
        float yn = plds[P][0][wv][lane] + plds[P][1][wv][lane] +
                   plds[P][2][wv][lane] + plds[P][3][wv][lane];

        // wave-uniform ls chain (sum of e_{j-1} written last step)
        f32x4 rv = redl[1 - P];
        float sum_prev = (rv[0] + rv[1]) + (rv[2] + rv[3]);
        float lsj = Mn + __logf(sum_prev);        // reference ls[j]
        if (j == len) out_r = lsj;
        float delta = lsj - ls_prev;
        ls_prev = lsj;
        float Mj = lsj + delta;                   // predicted normalizer for alpha_j
        float C = Mn;

        // alpha = C + log(S); S = sum_w y_w * exp(M_w + em_w - C)
        float S;
        {   float yv = yn;
            if (j == 0) yv = 256.0f;              // initial-state path (alpha_{-1}=0 over K)
            S = yv * __expf(Mn + em_cur[0] - C);
        }
        {   float yv = y1;
            if (j < 4) yv = (j == 1) ? 256.0f : ((j < 1) ? 0.0f : yv);
            S = fmaf(yv, __expf(M1 + em_cur[1] - C), S);
        }
        {   float yv = y2;
            if (j < 4) yv = (j == 2) ? 256.0f : ((j < 2) ? 0.0f : yv);
            S = fmaf(yv, __expf(M2 + em_cur[2] - C), S);
        }
        {   float yv = y3;
            if (j < 4) yv = (j == 3) ? 256.0f : ((j < 3) ? 0.0f : yv);
            S = fmaf(yv, __expf(M3 + em_cur[3] - C), S);
        }
        float e = S * __expf(C - Mj);             // exp(alpha_j - Mj), fits f16

        // pack pair for next step's readlane broadcast + wave sum of e
        float partner = __shfl_xor(e, 1, 64);
        float lo = (lane & 1) ? partner : e;
        float hi = (lane & 1) ? e : partner;
        pk = __builtin_bit_cast(uint32_t, __builtin_amdgcn_cvt_pkrtz(lo, hi));
        float ps = e + partner;
#pragma unroll
        for (int o = 2; o < 64; o <<= 1) ps += __shfl_xor(ps, o, 64);
        if (lane == 0) ((float*)&redl[P])[wv] = ps;  // consumed next step, after its barrier

        // ring shift + em rotate
        y3 = y2; y2 = y1; y1 = yn;
        M3 = M2; M2 = M1; M1 = Mn; Mn = Mj;
#pragma unroll
        for (int w = 0; w < 4; ++w)
            em_cur[w] = (lgn[w] + hcn[w]) * tm0;
    };

    for (int j = 0; j < CS; j += 2) {
        step(j,     std::integral_constant<int, 0>{});
        step(j + 1, std::integral_constant<int, 1>{});
    }

    __syncthreads();
    if (tid == 0) {
        f32x4 rv = redl[1];                       // j=127 wrote parity 1
        float tot = (rv[0] + rv[1]) + (rv[2] + rv[3]);
        float ls_full = Mn + __logf(tot);         // Mn = M_127
        if (len == CS) out_r = ls_full;
        out[b] = out_r;
    }
}

extern "C" void kernel_launch(void* const* d_in, const int* in_sizes, int n_in,
                              void* d_out, int out_size, void* d_ws, size_t ws_size,
                              hipStream_t stream) {
    const float* logits    = (const float*)d_in[0];
    const float* T         = (const float*)d_in[1];
    const float* ham       = (const float*)d_in[2];
    const float* tag_mask  = (const float*)d_in[3];
    const int*   text_mask = (const int*)d_in[4];
    float* out = (float*)d_out;

    crf_scan_kernel<<<CB, 256, 0, stream>>>(logits, T, ham, tag_mask, text_mask, out);
}

// Round 7
// 203.566 us; speedup vs baseline: 1.1600x; 1.0654x over previous
//
#include <hip/hip_runtime.h>
#include <type_traits>
#include <cstdint>

typedef __attribute__((ext_vector_type(2))) _Float16 half2;
typedef __attribute__((ext_vector_type(4))) float f32x4;
typedef __attribute__((ext_vector_type(16))) unsigned int u32x16;

constexpr int CB = 48, CS = 128, CW = 4, CK = 256;

__global__ __launch_bounds__(256, 1)
void crf_scan_kernel(const float* __restrict__ logits,
                     const float* __restrict__ T,
                     const float* __restrict__ ham,
                     const float* __restrict__ tag_mask,
                     const int* __restrict__ text_mask,
                     float* __restrict__ out) {
    const int b = blockIdx.x;
    const int tid = (int)threadIdx.x;
    const int wv = tid >> 6;      // wave: owns kp-chunk [64wv,64wv+64) and outputs k=64wv+lane
    const int lane = tid & 63;

    __shared__ float plds[2][4][4][64];  // [parity][src wave][g][lane] partial dots
    __shared__ f32x4 redl[2];            // per-wave partial sums of e, [parity]
    __shared__ int len_s;

    if (tid == 0) len_s = 0;
    __syncthreads();
    if (tid < CS) atomicAdd(&len_s, text_mask[b * CS + tid]);
    if (tid == 0) redl[1] = (f32x4){64.0f, 64.0f, 64.0f, 64.0f};  // sum e_{-1} = 256

    const float tm0 = tag_mask[(size_t)b * CK * CK + tid];  // tag_mask[b,0,k], k=tid

    // Register-resident transition slice as 8 named SSA vectors (NOT a C array —
    // arrays get demoted off the arch-VGPR file; see R4/R6 VGPR_Count=92/96).
    // Pair (g,i): eT[64g+lane][64wv+2i .. +1], i<16 in LO, i-16 in HI; eT = exp(T*tag_mask).
    u32x16 et0{}, et1{}, et2{}, et3{}, et4{}, et5{}, et6{}, et7{};
    {
        const float* Tb = T + (size_t)b * CK * CK;
        const float* mb = tag_mask + (size_t)b * CK * CK;
#define INIT_G(g, LO, HI) { \
        const float* tp = Tb + (64 * g + lane) * CK + 64 * wv; \
        const float* mp = mb + (64 * g + lane) * CK + 64 * wv; \
        _Pragma("unroll") \
        for (int i = 0; i < 16; ++i) { \
            float a0 = __expf(tp[2 * i] * mp[2 * i]); \
            float a1 = __expf(tp[2 * i + 1] * mp[2 * i + 1]); \
            LO[i] = __builtin_bit_cast(unsigned int, __builtin_amdgcn_cvt_pkrtz(a0, a1)); \
            float b0 = __expf(tp[32 + 2 * i] * mp[32 + 2 * i]); \
            float b1 = __expf(tp[32 + 2 * i + 1] * mp[32 + 2 * i + 1]); \
            HI[i] = __builtin_bit_cast(unsigned int, __builtin_amdgcn_cvt_pkrtz(b0, b1)); \
        } }
        INIT_G(0, et0, et1)
        INIT_G(1, et2, et3)
        INIT_G(2, et4, et5)
        INIT_G(3, et6, et7)
#undef INIT_G
    }

    const float* lgb = logits + (size_t)b * CS * CW * CK;
    const float* hcb = ham    + (size_t)b * CS * CW * CK;

    // wave-uniform scan state
    float Mn = 0.0f, M1 = 0.0f, M2 = 0.0f, M3 = 0.0f;  // normalizers of alpha_{j-1..j-4}
    float y1 = 0.0f, y2 = 0.0f, y3 = 0.0f;             // y(alpha_{j-2..j-4}) at this thread's k
    float ls_prev = __logf(256.0f) - 2.0f;             // seeds delta = 2 at j = 0
    float out_r = __logf(256.0f);                      // ls[0] (len == 0 case)

    float em_cur[4];
#pragma unroll
    for (int w = 0; w < 4; ++w)
        em_cur[w] = (lgb[w * CK + tid] + hcb[w * CK + tid]) * tm0;

    // packed e_{j-1} pair for this lane's 2-group; e_{-1} = ones
    uint32_t pk = 0x3c003c00u;  // (1.0h, 1.0h)

    __syncthreads();
    const int len = len_s;

    auto step = [&](int j, auto pc) {
        constexpr int P = pc.value;  // j & 1

        // dot phase: y_j partials over this wave's kp chunk, e broadcast via readlane->SGPR
        float ac[8] = {0, 0, 0, 0, 0, 0, 0, 0};
#pragma unroll
        for (int i = 0; i < 16; ++i) {
            uint32_t s0 = (uint32_t)__builtin_amdgcn_readlane((int)pk, 2 * i);
            uint32_t s1 = (uint32_t)__builtin_amdgcn_readlane((int)pk, 2 * i + 32);
            half2 h0 = __builtin_bit_cast(half2, s0);
            half2 h1 = __builtin_bit_cast(half2, s1);
            ac[0] = __builtin_amdgcn_fdot2(__builtin_bit_cast(half2, et0[i]), h0, ac[0], false);
            ac[4] = __builtin_amdgcn_fdot2(__builtin_bit_cast(half2, et1[i]), h1, ac[4], false);
            ac[1] = __builtin_amdgcn_fdot2(__builtin_bit_cast(half2, et2[i]), h0, ac[1], false);
            ac[5] = __builtin_amdgcn_fdot2(__builtin_bit_cast(half2, et3[i]), h1, ac[5], false);
            ac[2] = __builtin_amdgcn_fdot2(__builtin_bit_cast(half2, et4[i]), h0, ac[2], false);
            ac[6] = __builtin_amdgcn_fdot2(__builtin_bit_cast(half2, et5[i]), h1, ac[6], false);
            ac[3] = __builtin_amdgcn_fdot2(__builtin_bit_cast(half2, et6[i]), h0, ac[3], false);
            ac[7] = __builtin_amdgcn_fdot2(__builtin_bit_cast(half2, et7[i]), h1, ac[7], false);
        }

        // emission prefetch for j+1 (stays in flight across the barrier; no vmcnt drain)
        int jn = (j + 1 < CS) ? j + 1 : 0;
        float lgn[4], hcn[4];
#pragma unroll
        for (int w = 0; w < 4; ++w) {
            int idx = jn * (CW * CK) + w * CK + tid;
            lgn[w] = lgb[idx];
            hcn[w] = hcb[idx];
        }

        // publish partials (conflict-free: lane-stride 4B)
#pragma unroll
        for (int g = 0; g < 4; ++g)
            plds[P][wv][g][lane] = ac[g] + ac[g + 4];

        // drain LDS only; global loads stay in flight
        asm volatile("s_waitcnt expcnt(0) lgkmcnt(0)\n\ts_barrier" ::: "memory");

        // combine: y_j at this thread's k = 64*wv + lane
        float yn = plds[P][0][wv][lane] + plds[P][1][wv][lane] +
                   plds[P][2][wv][lane] + plds[P][3][wv][lane];

        // wave-uniform ls chain (sum of e_{j-1} written last step)
        f32x4 rv = redl[1 - P];
        float sum_prev = (rv[0] + rv[1]) + (rv[2] + rv[3]);
        float lsj = Mn + __logf(sum_prev);        // reference ls[j]
        if (j == len) out_r = lsj;
        float delta = lsj - ls_prev;
        ls_prev = lsj;
        float Mj = lsj + delta;                   // predicted normalizer for alpha_j
        float C = Mn;

        // alpha = C + log(S); S = sum_w y_w * exp(M_w + em_w - C)
        float S;
        {   float yv = yn;
            if (j == 0) yv = 256.0f;              // initial-state path (alpha_{-1}=0 over K)
            S = yv * __expf(Mn + em_cur[0] - C);
        }
        {   float yv = y1;
            if (j < 4) yv = (j == 1) ? 256.0f : ((j < 1) ? 0.0f : yv);
            S = fmaf(yv, __expf(M1 + em_cur[1] - C), S);
        }
        {   float yv = y2;
            if (j < 4) yv = (j == 2) ? 256.0f : ((j < 2) ? 0.0f : yv);
            S = fmaf(yv, __expf(M2 + em_cur[2] - C), S);
        }
        {   float yv = y3;
            if (j < 4) yv = (j == 3) ? 256.0f : ((j < 3) ? 0.0f : yv);
            S = fmaf(yv, __expf(M3 + em_cur[3] - C), S);
        }
        float e = S * __expf(C - Mj);             // exp(alpha_j - Mj), fits f16

        // pack pair for next step's readlane broadcast + wave sum of e
        float partner = __shfl_xor(e, 1, 64);
        float lo = (lane & 1) ? partner : e;
        float hi = (lane & 1) ? e : partner;
        pk = __builtin_bit_cast(uint32_t, __builtin_amdgcn_cvt_pkrtz(lo, hi));
        float ps = e + partner;
#pragma unroll
        for (int o = 2; o < 64; o <<= 1) ps += __shfl_xor(ps, o, 64);
        if (lane == 0) ((float*)&redl[P])[wv] = ps;  // consumed next step, after its barrier

        // ring shift + em rotate
        y3 = y2; y2 = y1; y1 = yn;
        M3 = M2; M2 = M1; M1 = Mn; Mn = Mj;
#pragma unroll
        for (int w = 0; w < 4; ++w)
            em_cur[w] = (lgn[w] + hcn[w]) * tm0;
    };

    for (int j = 0; j < CS; j += 2) {
        step(j,     std::integral_constant<int, 0>{});
        step(j + 1, std::integral_constant<int, 1>{});
    }

    __syncthreads();
    if (tid == 0) {
        f32x4 rv = redl[1];                       // j=127 wrote parity 1
        float tot = (rv[0] + rv[1]) + (rv[2] + rv[3]);
        float ls_full = Mn + __logf(tot);         // Mn = M_127
        if (len == CS) out_r = ls_full;
        out[b] = out_r;
    }
}

extern "C" void kernel_launch(void* const* d_in, const int* in_sizes, int n_in,
                              void* d_out, int out_size, void* d_ws, size_t ws_size,
                              hipStream_t stream) {
    const float* logits    = (const float*)d_in[0];
    const float* T         = (const float*)d_in[1];
    const float* ham       = (const float*)d_in[2];
    const float* tag_mask  = (const float*)d_in[3];
    const int*   text_mask = (const int*)d_in[4];
    float* out = (float*)d_out;

    crf_scan_kernel<<<CB, 256, 0, stream>>>(logits, T, ham, tag_mask, text_mask, out);
}

// Round 8
// 203.487 us; speedup vs baseline: 1.1604x; 1.0004x over previous
//
#include <hip/hip_runtime.h>
#include <type_traits>
#include <cstdint>

typedef __attribute__((ext_vector_type(2))) _Float16 half2;
typedef __attribute__((ext_vector_type(4))) float f32x4;
typedef __attribute__((ext_vector_type(4))) unsigned int u32x4;
typedef __attribute__((ext_vector_type(16))) unsigned int u32x16;

constexpr int CB = 48, CS = 128, CW = 4, CK = 256;

__global__ __launch_bounds__(512, 2)
void crf_scan_kernel(const float* __restrict__ logits,
                     const float* __restrict__ T,
                     const float* __restrict__ ham,
                     const float* __restrict__ tag_mask,
                     const int* __restrict__ text_mask,
                     float* __restrict__ out) {
    const int b = blockIdx.x;
    const int tid = (int)threadIdx.x;
    const int w8 = tid >> 6;        // wave 0..7: owns kp-chunk [32*w8, 32*w8+32)
    const int lane = tid & 63;
    const bool epi = (tid < CK);    // waves 0..3 additionally run the epilogue for k = tid

    __shared__ alignas(16) unsigned short ebuf16[CK];  // e_{j-1} as f16
    __shared__ float plds[4][8][64];                   // [g][w][lane] dot partials for row 64g+lane
    __shared__ alignas(16) float pldo[8];              // per-wave partial of sum(e_{j-1})
    __shared__ float red4[4];
    __shared__ int len_s;

    if (tid == 0) len_s = 0;
    __syncthreads();
    if (tid < CS) atomicAdd(&len_s, text_mask[b * CS + tid]);
    if (tid < CK) ebuf16[tid] = 0x3C00;  // e_{-1} = 1.0h (alpha_{-1} = 0, M_{-1} = 0)

    const float tm0 = tag_mask[(size_t)b * CK * CK + (tid & (CK - 1))];  // tag_mask[b,0,k]

    // et table: thread (w8,lane) holds rows k = 64g+lane (g=0..3), kp pairs over [32*w8,+32).
    // Named SSA vectors, 64 dwords/thread.
    u32x16 et0{}, et1{}, et2{}, et3{};
    {
        const float* Tb = T + (size_t)b * CK * CK;
        const float* mb = tag_mask + (size_t)b * CK * CK;
#define INIT_G(g, V) { \
        const float* tp = Tb + (64 * g + lane) * CK + 32 * w8; \
        const float* mp = mb + (64 * g + lane) * CK + 32 * w8; \
        _Pragma("unroll") \
        for (int i = 0; i < 16; ++i) { \
            float a0 = __expf(tp[2 * i] * mp[2 * i]); \
            float a1 = __expf(tp[2 * i + 1] * mp[2 * i + 1]); \
            V[i] = __builtin_bit_cast(unsigned int, __builtin_amdgcn_cvt_pkrtz(a0, a1)); \
        } }
        INIT_G(0, et0) INIT_G(1, et1) INIT_G(2, et2) INIT_G(3, et3)
#undef INIT_G
    }

    const float* lgb = logits + (size_t)b * CS * CW * CK;
    const float* hcb = ham    + (size_t)b * CS * CW * CK;

    // epilogue-wave scan state (wave-uniform within waves 0..3)
    float Mn = 0.0f, M1 = 0.0f, M2 = 0.0f, M3 = 0.0f;
    float y1 = 0.0f, y2 = 0.0f, y3 = 0.0f;
    float ls_prev = __logf(256.0f) - 2.0f;  // seeds delta = 2 at j = 0
    float out_r = __logf(256.0f);           // ls[0] (len == 0 case)
    float e_last = 0.0f;

    float em_cur[4];
    if (epi) {
#pragma unroll
        for (int w = 0; w < 4; ++w)
            em_cur[w] = (lgb[w * CK + tid] + hcb[w * CK + tid]) * tm0;
    }

    __syncthreads();
    const int len = len_s;
    const half2 ones = {(_Float16)1.0f, (_Float16)1.0f};

    for (int j = 0; j < CS; ++j) {
        // --- dot phase: all 8 waves ---
        // e-chunk broadcast read (wave-uniform addresses, conflict-free)
        u32x4 evq0 = *(const u32x4*)(&ebuf16[32 * w8]);
        u32x4 evq1 = *(const u32x4*)(&ebuf16[32 * w8 + 8]);
        u32x4 evq2 = *(const u32x4*)(&ebuf16[32 * w8 + 16]);
        u32x4 evq3 = *(const u32x4*)(&ebuf16[32 * w8 + 24]);

        // emission prefetch for j+1 (in flight across both raw barriers)
        int jn = (j + 1 < CS) ? j + 1 : 0;
        float lgn[4], hcn[4];
        if (epi) {
#pragma unroll
            for (int w = 0; w < 4; ++w) {
                int idx = jn * (CW * CK) + w * CK + tid;
                lgn[w] = lgb[idx];
                hcn[w] = hcb[idx];
            }
        }

        float ac0 = 0.0f, ac1 = 0.0f, ac2 = 0.0f, ac3 = 0.0f, aco = 0.0f;
#define DOT4(EVQ, base) \
        _Pragma("unroll") \
        for (int i = 0; i < 4; ++i) { \
            half2 h = __builtin_bit_cast(half2, EVQ[i]); \
            ac0 = __builtin_amdgcn_fdot2(__builtin_bit_cast(half2, et0[base + i]), h, ac0, false); \
            ac1 = __builtin_amdgcn_fdot2(__builtin_bit_cast(half2, et1[base + i]), h, ac1, false); \
            ac2 = __builtin_amdgcn_fdot2(__builtin_bit_cast(half2, et2[base + i]), h, ac2, false); \
            ac3 = __builtin_amdgcn_fdot2(__builtin_bit_cast(half2, et3[base + i]), h, ac3, false); \
            aco = __builtin_amdgcn_fdot2(ones, h, aco, false); \
        }
        DOT4(evq0, 0) DOT4(evq1, 4) DOT4(evq2, 8) DOT4(evq3, 12)
#undef DOT4

        plds[0][w8][lane] = ac0;
        plds[1][w8][lane] = ac1;
        plds[2][w8][lane] = ac2;
        plds[3][w8][lane] = ac3;
        if (lane == 0) pldo[w8] = aco;

        // B1: partials visible; drain LDS only, global loads stay in flight
        asm volatile("s_waitcnt expcnt(0) lgkmcnt(0)\n\ts_barrier" ::: "memory");

        // --- epilogue phase: waves 0..3, k = tid ---
        if (epi) {
            const int g = tid >> 6;
            float yn = ((plds[g][0][lane] + plds[g][1][lane]) +
                        (plds[g][2][lane] + plds[g][3][lane])) +
                       ((plds[g][4][lane] + plds[g][5][lane]) +
                        (plds[g][6][lane] + plds[g][7][lane]));
            f32x4 po0 = *(const f32x4*)(&pldo[0]);
            f32x4 po1 = *(const f32x4*)(&pldo[4]);
            float sum_prev = ((po0[0] + po0[1]) + (po0[2] + po0[3])) +
                             ((po1[0] + po1[1]) + (po1[2] + po1[3]));

            float lsj = Mn + __logf(sum_prev);   // reference ls[j]
            if (j == len) out_r = lsj;
            float delta = lsj - ls_prev;
            ls_prev = lsj;
            float Mj = lsj + delta;              // predicted normalizer for alpha_j
            float C = Mn;

            // alpha = C + log(S); S = sum_w y_w * exp(M_w + em_w - C)
            float S;
            {   float yv = yn;
                if (j == 0) yv = 256.0f;         // initial-state path (alpha_{-1}=0 over K)
                S = yv * __expf(Mn + em_cur[0] - C);
            }
            {   float yv = y1;
                if (j < 4) yv = (j == 1) ? 256.0f : ((j < 1) ? 0.0f : yv);
                S = fmaf(yv, __expf(M1 + em_cur[1] - C), S);
            }
            {   float yv = y2;
                if (j < 4) yv = (j == 2) ? 256.0f : ((j < 2) ? 0.0f : yv);
                S = fmaf(yv, __expf(M2 + em_cur[2] - C), S);
            }
            {   float yv = y3;
                if (j < 4) yv = (j == 3) ? 256.0f : ((j < 3) ? 0.0f : yv);
                S = fmaf(yv, __expf(M3 + em_cur[3] - C), S);
            }
            float e = S * __expf(C - Mj);        // exp(alpha_j - Mj), fits f16
            ebuf16[tid] = __builtin_bit_cast(unsigned short, (_Float16)e);
            e_last = e;

            // ring shift + em rotate
            y3 = y2; y2 = y1; y1 = yn;
            M3 = M2; M2 = M1; M1 = Mn; Mn = Mj;
#pragma unroll
            for (int w = 0; w < 4; ++w)
                em_cur[w] = (lgn[w] + hcn[w]) * tm0;
        }

        // B2: new e row visible before next step's dot reads
        asm volatile("s_waitcnt expcnt(0) lgkmcnt(0)\n\ts_barrier" ::: "memory");
    }

    // ls[128] = M_127 + log(sum_k e_127)
    if (epi) {
        float ps = e_last;
#pragma unroll
        for (int o = 1; o < 64; o <<= 1) ps += __shfl_xor(ps, o, 64);
        if (lane == 0) red4[tid >> 6] = ps;
    }
    __syncthreads();
    if (tid == 0) {
        float tot = (red4[0] + red4[1]) + (red4[2] + red4[3]);
        float ls_full = Mn + __logf(tot);
        if (len == CS) out_r = ls_full;
        out[b] = out_r;
    }
}

extern "C" void kernel_launch(void* const* d_in, const int* in_sizes, int n_in,
                              void* d_out, int out_size, void* d_ws, size_t ws_size,
                              hipStream_t stream) {
    const float* logits    = (const float*)d_in[0];
    const float* T         = (const float*)d_in[1];
    const float* ham       = (const float*)d_in[2];
    const float* tag_mask  = (const float*)d_in[3];
    const int*   text_mask = (const int*)d_in[4];
    float* out = (float*)d_out;

    crf_scan_kernel<<<CB, 512, 0, stream>>>(logits, T, ham, tag_mask, text_mask, out);
}